// Round 5
// baseline (159.350 us; speedup 1.0000x reference)
//
#include <hip/hip_runtime.h>
#include <hip/hip_bf16.h>
#include <stdint.h>

// B=16, K=8, N=196, D=768, H=3072, DOUT=768
// y[b,n,:] = (mean_k relu(slots[b,k]@W1 + pos[n]@W1 + b1)) @ W2 + b2
// (softmax over K of K-identical values is exactly 1/K; map_alpha unused)
//
// 3 dispatches:
//  K1: GEMM1 (C1[324x3072] = [slots;pos]@W1, f32 inputs converted in-register,
//      XOR-swizzled LDS) + W2->W2t atom-tiled bf16 conversion (extra blocks).
//  K2: hbar -> Hb atoms (GEMM2 A-operand layout).
//  K3: out = Hb@W2t^T + b2. BK=128, 64KB double-buffered global_load_lds
//      pipeline with fine vmcnt, direct stores (no atomics/bounds).
// Atom = 64x64 bf16 tile, image [kb 0..7][r 0..63] chunks of 8; off=(kb*64+r)*8.

typedef __attribute__((ext_vector_type(8))) short bf16x8;
typedef __attribute__((ext_vector_type(4))) float f32x4;

#define AS1 __attribute__((address_space(1)))
#define AS3 __attribute__((address_space(3)))

#define WAIT_VM(N) asm volatile("s_waitcnt vmcnt(" #N ")" ::: "memory")
#define BAR()      asm volatile("s_barrier" ::: "memory")
#define BAR_LDS()  asm volatile("s_waitcnt lgkmcnt(0)\ns_barrier" ::: "memory")

static __device__ __forceinline__ void gld_lds16(const void* g, void* l) {
    __builtin_amdgcn_global_load_lds((const AS1 unsigned int*)g,
                                     (AS3 unsigned int*)l, 16, 0, 0);
}

static __device__ __forceinline__ unsigned short f2bf(float f) {
    union { float f; unsigned int u; } v; v.f = f;
    unsigned int u = v.u;
    return (unsigned short)((u + 0x7fffu + ((u >> 16) & 1u)) >> 16);  // RNE
}

static __device__ __forceinline__ uint4 pk8(float4 a, float4 b) {
    uint4 o;
    o.x = (unsigned int)f2bf(a.x) | ((unsigned int)f2bf(a.y) << 16);
    o.y = (unsigned int)f2bf(a.z) | ((unsigned int)f2bf(a.w) << 16);
    o.z = (unsigned int)f2bf(b.x) | ((unsigned int)f2bf(b.y) << 16);
    o.w = (unsigned int)f2bf(b.z) | ((unsigned int)f2bf(b.w) << 16);
    return o;
}

// ---------------- K1: fused GEMM1 + W2t conversion ----------------
// blocks 0..143: GEMM1, BM=64 (rt=bx/24), BN=128 (cx=bx%24), K=768.
// blocks 144..1295: W2 (3072x768 f32) -> W2t atoms [12 rowAtoms][48 kt].
__launch_bounds__(256)
__global__ void k_phase1(const float* __restrict__ slots, const float* __restrict__ pos,
                         const float* __restrict__ W1, float* __restrict__ C1,
                         const float* __restrict__ W2, unsigned short* __restrict__ W2t) {
    const int tid = threadIdx.x;
    const int bx  = blockIdx.x;

    if (bx >= 144) {                       // ---- W2t conversion ----
        int idx = (bx - 144) * 256 + tid;  // 0..294911
        int r  = idx % 768;                // dout col (row of W2t)
        int kc = idx / 768;                // 8-elem k chunk, 0..383
        unsigned int po[4];
        #pragma unroll
        for (int j = 0; j < 4; ++j) {
            unsigned short lo = f2bf(W2[(size_t)(kc * 8 + 2 * j) * 768 + r]);
            unsigned short hi = f2bf(W2[(size_t)(kc * 8 + 2 * j + 1) * 768 + r]);
            po[j] = (unsigned int)lo | ((unsigned int)hi << 16);
        }
        size_t dst = ((size_t)(r >> 6) * 48 + (kc >> 3)) * 4096
                   + (size_t)((kc & 7) * 64 + (r & 63)) * 8;
        *(uint4*)(W2t + dst) = make_uint4(po[0], po[1], po[2], po[3]);
        return;
    }

    // ---- GEMM1 ----
    __shared__ unsigned short sm[12288];   // A 4096 elems | B 8192 elems (24 KB)
    const int lane = tid & 63;
    const int wave = tid >> 6;
    const int wm = wave >> 1, wn = wave & 1;
    const int q = lane >> 4, l16 = lane & 15;
    const int cx = bx % 24, rt = bx / 24;
    const int col0 = cx * 128;

    f32x4 acc[2][4] = {};

    for (int k0 = 0; k0 < 768; k0 += 64) {
        __syncthreads();
        // A tile 64m x 64k: 512 chunks; chunk c: m=c&63, kb=c>>6
        #pragma unroll
        for (int it = 0; it < 2; ++it) {
            int c = it * 256 + tid;
            int m = c & 63, kb = c >> 6;
            int r = rt * 64 + m; if (r > 323) r = 323;   // clamped rows never stored
            const float* src = (r < 128 ? slots + (size_t)r * 768
                                        : pos + (size_t)(r - 128) * 768) + k0 + kb * 8;
            float4 a = *(const float4*)src;
            float4 b = *(const float4*)(src + 4);
            *(uint4*)(&sm[m * 64 + ((kb ^ (m & 7)) * 8)]) = pk8(a, b);
        }
        // B tile 64k x 128n from W1 (k-major rows): 1024 chunks; c: n=c&127, kb=c>>7
        #pragma unroll
        for (int it = 0; it < 4; ++it) {
            int c = it * 256 + tid;
            int n = c & 127, kb = c >> 7;
            const float* src = W1 + (size_t)(k0 + kb * 8) * 3072 + col0 + n;
            float4 a, b;
            a.x = src[0];        a.y = src[3072];     a.z = src[2 * 3072]; a.w = src[3 * 3072];
            b.x = src[4 * 3072]; b.y = src[5 * 3072]; b.z = src[6 * 3072]; b.w = src[7 * 3072];
            *(uint4*)(&sm[4096 + n * 64 + ((kb ^ (n & 7)) * 8)]) = pk8(a, b);
        }
        __syncthreads();
        #pragma unroll
        for (int ks = 0; ks < 2; ++ks) {
            const int kq = ks * 4 + q;
            bf16x8 af[2], bfr[4];
            #pragma unroll
            for (int ii = 0; ii < 2; ++ii) {
                int m = wm * 32 + ii * 16 + l16;
                af[ii] = *(const bf16x8*)(&sm[m * 64 + ((kq ^ (m & 7)) * 8)]);
            }
            #pragma unroll
            for (int jj = 0; jj < 4; ++jj) {
                int n = wn * 64 + jj * 16 + l16;
                bfr[jj] = *(const bf16x8*)(&sm[4096 + n * 64 + ((kq ^ (n & 7)) * 8)]);
            }
            #pragma unroll
            for (int ii = 0; ii < 2; ++ii)
                #pragma unroll
                for (int jj = 0; jj < 4; ++jj)
                    acc[ii][jj] = __builtin_amdgcn_mfma_f32_16x16x32_bf16(
                        af[ii], bfr[jj], acc[ii][jj], 0, 0, 0);
        }
    }
    // epilogue: C/D col=lane&15, row=(lane>>4)*4+reg
    #pragma unroll
    for (int ii = 0; ii < 2; ++ii) {
        #pragma unroll
        for (int jj = 0; jj < 4; ++jj) {
            int col = col0 + wn * 64 + jj * 16 + l16;
            #pragma unroll
            for (int r = 0; r < 4; ++r) {
                int row = rt * 64 + wm * 32 + ii * 16 + q * 4 + r;
                if (row < 324) C1[(size_t)row * 3072 + col] = acc[ii][jj][r];
            }
        }
    }
}

// ---- K2: hbar[bn,h] = 0.125 * sum_k relu(s1+p1+b1) -> Hb atoms (GEMM2 A layout) ----
__global__ void k_hbar(const float* __restrict__ C1, const float* __restrict__ b1,
                       unsigned short* __restrict__ Hb) {
    const int lane = threadIdx.x & 63;
    const int wv   = threadIdx.x >> 6;
    const int hc   = blockIdx.y * 4 + wv;          // 0..383
    const int h0   = hc * 8;
    const int bn   = blockIdx.x * 64 + lane;       // 0..3135
    const int b    = bn / 196;
    const int n    = bn - b * 196;
    const float* prow = C1 + (size_t)(128 + n) * 3072 + h0;
    float4 pA = *(const float4*)(prow);
    float4 pB = *(const float4*)(prow + 4);
    float4 bA = *(const float4*)(b1 + h0);
    float4 bB = *(const float4*)(b1 + h0 + 4);
    float pb[8] = { pA.x + bA.x, pA.y + bA.y, pA.z + bA.z, pA.w + bA.w,
                    pB.x + bB.x, pB.y + bB.y, pB.z + bB.z, pB.w + bB.w };
    float acc[8] = {};
    #pragma unroll
    for (int k = 0; k < 8; ++k) {
        const float* srow = C1 + (size_t)(b * 8 + k) * 3072 + h0;  // wave-broadcast
        float4 sA_ = *(const float4*)(srow);
        float4 sB_ = *(const float4*)(srow + 4);
        acc[0] += fmaxf(sA_.x + pb[0], 0.f);
        acc[1] += fmaxf(sA_.y + pb[1], 0.f);
        acc[2] += fmaxf(sA_.z + pb[2], 0.f);
        acc[3] += fmaxf(sA_.w + pb[3], 0.f);
        acc[4] += fmaxf(sB_.x + pb[4], 0.f);
        acc[5] += fmaxf(sB_.y + pb[5], 0.f);
        acc[6] += fmaxf(sB_.z + pb[6], 0.f);
        acc[7] += fmaxf(sB_.w + pb[7], 0.f);
    }
    unsigned int w0 = (unsigned int)f2bf(acc[0] * 0.125f) | ((unsigned int)f2bf(acc[1] * 0.125f) << 16);
    unsigned int w1 = (unsigned int)f2bf(acc[2] * 0.125f) | ((unsigned int)f2bf(acc[3] * 0.125f) << 16);
    unsigned int w2 = (unsigned int)f2bf(acc[4] * 0.125f) | ((unsigned int)f2bf(acc[5] * 0.125f) << 16);
    unsigned int w3 = (unsigned int)f2bf(acc[6] * 0.125f) | ((unsigned int)f2bf(acc[7] * 0.125f) << 16);
    size_t dst = ((size_t)blockIdx.x * 48 + (hc >> 3)) * 4096
               + (size_t)((hc & 7) * 64 + lane) * 8;
    *(uint4*)(Hb + dst) = make_uint4(w0, w1, w2, w3);
}

// ---- K3: out = Hb @ W2t^T + b2. BM=BN=64, BK=128, dbuf pipeline ----
// Hb atoms [rt 49][kt 48]; W2t atoms [nt 12][kt 48]. grid (12, 49).
__launch_bounds__(256)
__global__ void k_gemm2(const unsigned short* __restrict__ Hb,
                        const unsigned short* __restrict__ W2t,
                        const float* __restrict__ b2, float* __restrict__ out) {
    __shared__ unsigned short sm[2 * 16384];   // 64 KB: [buf][A 8192 | B 8192]
    const int tid  = threadIdx.x;
    const int lane = tid & 63;
    const int wave = tid >> 6;
    const int wm = wave >> 1, wn = wave & 1;
    const int q = lane >> 4, l16 = lane & 15;
    const int nt = blockIdx.x, rt = blockIdx.y;

    const unsigned short* Ab = Hb  + (size_t)rt * 48 * 4096;
    const unsigned short* Bb = W2t + (size_t)nt * 48 * 4096;

    f32x4 acc[2][2] = {};

    auto stage = [&](int i, unsigned short* dst) {     // 2 A atoms + 2 B atoms (32 KB)
        const unsigned short* Ag = Ab + (size_t)i * 8192;
        const unsigned short* Bg = Bb + (size_t)i * 8192;
        #pragma unroll
        for (int u = 0; u < 4; ++u)
            gld_lds16(Ag + u * 2048 + tid * 8, dst + u * 2048 + tid * 8);
        #pragma unroll
        for (int u = 0; u < 4; ++u)
            gld_lds16(Bg + u * 2048 + tid * 8, dst + 8192 + u * 2048 + tid * 8);
    };

    auto compute = [&](const unsigned short* buf) {
        #pragma unroll
        for (int a = 0; a < 2; ++a) {
            #pragma unroll
            for (int ks = 0; ks < 2; ++ks) {
                const int kb = a * 4096 + (ks * 4 + q) * 512;
                bf16x8 af[2], bfr[2];
                af[0]  = *(const bf16x8*)(buf + kb + (wm * 32 + l16) * 8);
                af[1]  = *(const bf16x8*)(buf + kb + (wm * 32 + 16 + l16) * 8);
                bfr[0] = *(const bf16x8*)(buf + 8192 + kb + (wn * 32 + l16) * 8);
                bfr[1] = *(const bf16x8*)(buf + 8192 + kb + (wn * 32 + 16 + l16) * 8);
                #pragma unroll
                for (int ii = 0; ii < 2; ++ii)
                    #pragma unroll
                    for (int jj = 0; jj < 2; ++jj)
                        acc[ii][jj] = __builtin_amdgcn_mfma_f32_16x16x32_bf16(
                            af[ii], bfr[jj], acc[ii][jj], 0, 0, 0);
            }
        }
    };

    stage(0, sm);
    for (int i = 0; i < 24; i += 2) {
        if (i + 1 < 24) { stage(i + 1, sm + 16384); WAIT_VM(8); }
        else            { WAIT_VM(0); }
        BAR();
        compute(sm);
        BAR_LDS();
        if (i + 2 < 24) { stage(i + 2, sm); WAIT_VM(8); }
        else            { WAIT_VM(0); }
        BAR();
        compute(sm + 16384);
        if (i + 2 < 24) BAR_LDS();
    }

    // epilogue: 3136 x 768 exact -> no bounds checks
    const int row0 = rt * 64 + wm * 32;
    const int col0 = nt * 64 + wn * 32;
    #pragma unroll
    for (int ii = 0; ii < 2; ++ii) {
        #pragma unroll
        for (int jj = 0; jj < 2; ++jj) {
            int col = col0 + jj * 16 + l16;
            float bv = b2[col];
            #pragma unroll
            for (int r = 0; r < 4; ++r) {
                int row = row0 + ii * 16 + q * 4 + r;
                out[(size_t)row * 768 + col] = acc[ii][jj][r] + bv;
            }
        }
    }
}

extern "C" void kernel_launch(void* const* d_in, const int* in_sizes, int n_in,
                              void* d_out, int out_size, void* d_ws, size_t ws_size,
                              hipStream_t stream) {
    const float* slots  = (const float*)d_in[0];   // 16*8*768
    const float* pos    = (const float*)d_in[1];   // 196*768
    // d_in[2] = map_alpha: unused (softmax over K of identical values = 1/K)
    const float* W1     = (const float*)d_in[3];   // 768*3072
    const float* b1     = (const float*)d_in[4];   // 3072
    const float* W2     = (const float*)d_in[5];   // 3072*768
    const float* b2     = (const float*)d_in[6];   // 768
    float* out = (float*)d_out;                    // 3136*768 f32

    size_t off = 0;
    auto alloc = [&](size_t bytes) {
        void* p = (char*)d_ws + off;
        off += (bytes + 255) & ~(size_t)255;
        return p;
    };
    unsigned short* W2t = (unsigned short*)alloc((size_t)768 * 3072 * 2);   // [12][48] atoms
    float*          C1  = (float*)alloc((size_t)384 * 3072 * 4);            // row-major
    unsigned short* Hb  = (unsigned short*)alloc((size_t)3136 * 3072 * 2);  // [49][48] atoms

    // K1: GEMM1 (144 blocks) + W2t conversion (1152 blocks)
    k_phase1<<<1296, 256, 0, stream>>>(slots, pos, W1, C1, W2, W2t);
    // K2: hbar -> Hb atoms
    k_hbar<<<dim3(49, 96), 256, 0, stream>>>(C1, b1, Hb);
    // K3: out = Hb @ W2t^T + b2
    k_gemm2<<<dim3(12, 49), 256, 0, stream>>>(Hb, W2t, b2, out);
}

// Round 6
// 137.307 us; speedup vs baseline: 1.1605x; 1.1605x over previous
//
#include <hip/hip_runtime.h>
#include <hip/hip_bf16.h>
#include <stdint.h>

// B=16, K=8, N=196, D=768, H=3072, DOUT=768
// y[b,n,:] = (mean_k relu(slots[b,k]@W1 + pos[n]@W1 + b1)) @ W2 + b2
// (softmax over K of K-identical values is exactly 1/K; map_alpha unused)
//
// R3 structure (best so far) + 3-stage GEMM pipeline:
//  k_prep: W1->W1t, W2->W2t atom-tiled bf16, A1=[slots;pos] atom-tiled bf16
//  gemm_tiled: C1 = A1 @ W1t^T          (324x3072, KT=12)
//  k_hbar: Hb atoms = mean_k relu(...)  (GEMM2 A layout)
//  gemm_tiled: out = Hb @ W2t^T + b2    (3136x768, KT=48)
// Atom = 64x64 bf16 tile, image [kb 0..7][r 0..63] chunks of 8; off=(kb*64+r)*8.
// 3-stage: buffers t%3, stage(t+2) issued before waiting on stage(t) ->
// vmcnt(8) steady state, load latency hidden by 2 compute intervals.

typedef __attribute__((ext_vector_type(8))) short bf16x8;
typedef __attribute__((ext_vector_type(4))) float f32x4;

#define AS1 __attribute__((address_space(1)))
#define AS3 __attribute__((address_space(3)))

#define WAIT_VM(N) asm volatile("s_waitcnt vmcnt(" #N ")" ::: "memory")
#define BAR()      asm volatile("s_barrier" ::: "memory")
#define BAR_LDS()  asm volatile("s_waitcnt lgkmcnt(0)\ns_barrier" ::: "memory")

static __device__ __forceinline__ void gld_lds16(const void* g, void* l) {
    __builtin_amdgcn_global_load_lds((const AS1 unsigned int*)g,
                                     (AS3 unsigned int*)l, 16, 0, 0);
}

static __device__ __forceinline__ unsigned short f2bf(float f) {
    union { float f; unsigned int u; } v; v.f = f;
    unsigned int u = v.u;
    return (unsigned short)((u + 0x7fffu + ((u >> 16) & 1u)) >> 16);  // RNE
}

// ---------------- prep: W1t / W2t tiled transposes + A1 tiled pack ----------------
static __device__ __forceinline__ void conv_tiled(const float* __restrict__ W,
                                                  unsigned short* __restrict__ Wt,
                                                  int Kd, int Rd, int idx) {
    int r  = idx % Rd;                 // consecutive tid -> consecutive r (coalesced)
    int kc = idx / Rd;                 // 8-elem k-chunk
    unsigned int po[4];
    #pragma unroll
    for (int j = 0; j < 4; ++j) {
        unsigned short lo = f2bf(W[(size_t)(kc * 8 + 2 * j) * Rd + r]);
        unsigned short hi = f2bf(W[(size_t)(kc * 8 + 2 * j + 1) * Rd + r]);
        po[j] = (unsigned int)lo | ((unsigned int)hi << 16);
    }
    size_t dst = ((size_t)(r >> 6) * (Kd >> 6) + (kc >> 3)) * 4096
               + (size_t)((kc & 7) * 64 + (r & 63)) * 8;
    *(uint4*)(Wt + dst) = make_uint4(po[0], po[1], po[2], po[3]);
}

__global__ void k_prep(const float* __restrict__ W1, unsigned short* __restrict__ W1t,
                       const float* __restrict__ W2, unsigned short* __restrict__ W2t,
                       const float* __restrict__ S, const float* __restrict__ P,
                       unsigned short* __restrict__ A1) {
    int idx = blockIdx.x * blockDim.x + threadIdx.x;
    const int C1n = 96 * 3072;          // W1t tasks
    const int C2n = 384 * 768;          // W2t tasks
    const int PKn = 96 * 384;           // A1 tasks
    if (idx < C1n) {
        conv_tiled(W1, W1t, 768, 3072, idx);
    } else if (idx < C1n + C2n) {
        conv_tiled(W2, W2t, 3072, 768, idx - C1n);
    } else if (idx < C1n + C2n + PKn) {
        int t = idx - C1n - C2n;
        int r  = t % 384;
        int kc = t / 384;
        uint4 o = make_uint4(0u, 0u, 0u, 0u);
        if (r < 324) {
            const float* src = (r < 128) ? (S + (size_t)r * 768 + kc * 8)
                                         : (P + (size_t)(r - 128) * 768 + kc * 8);
            float4 a = *(const float4*)(src);
            float4 b = *(const float4*)(src + 4);
            o.x = (unsigned int)f2bf(a.x) | ((unsigned int)f2bf(a.y) << 16);
            o.y = (unsigned int)f2bf(a.z) | ((unsigned int)f2bf(a.w) << 16);
            o.z = (unsigned int)f2bf(b.x) | ((unsigned int)f2bf(b.y) << 16);
            o.w = (unsigned int)f2bf(b.z) | ((unsigned int)f2bf(b.w) << 16);
        }
        size_t dst = ((size_t)(r >> 6) * 12 + (kc >> 3)) * 4096
                   + (size_t)((kc & 7) * 64 + (r & 63)) * 8;
        *(uint4*)(A1 + dst) = o;
    }
}

// ---- hbar: one wave = 64 consecutive bn x 8 h; writes GEMM2's tiled A layout ----
__global__ void k_hbar(const float* __restrict__ C1, const float* __restrict__ b1,
                       unsigned short* __restrict__ Hb) {
    const int lane = threadIdx.x & 63;
    const int wv   = threadIdx.x >> 6;
    const int hc   = blockIdx.y * 4 + wv;          // 0..383
    const int h0   = hc * 8;
    const int bn   = blockIdx.x * 64 + lane;       // 0..3135
    const int b    = bn / 196;
    const int n    = bn - b * 196;
    const float* prow = C1 + (size_t)(128 + n) * 3072 + h0;
    float4 pA = *(const float4*)(prow);
    float4 pB = *(const float4*)(prow + 4);
    float4 bA = *(const float4*)(b1 + h0);
    float4 bB = *(const float4*)(b1 + h0 + 4);
    float pb[8] = { pA.x + bA.x, pA.y + bA.y, pA.z + bA.z, pA.w + bA.w,
                    pB.x + bB.x, pB.y + bB.y, pB.z + bB.z, pB.w + bB.w };
    float acc[8] = {};
    #pragma unroll
    for (int k = 0; k < 8; ++k) {
        const float* srow = C1 + (size_t)(b * 8 + k) * 3072 + h0;  // wave-broadcast
        float4 sA_ = *(const float4*)(srow);
        float4 sB_ = *(const float4*)(srow + 4);
        acc[0] += fmaxf(sA_.x + pb[0], 0.f);
        acc[1] += fmaxf(sA_.y + pb[1], 0.f);
        acc[2] += fmaxf(sA_.z + pb[2], 0.f);
        acc[3] += fmaxf(sA_.w + pb[3], 0.f);
        acc[4] += fmaxf(sB_.x + pb[4], 0.f);
        acc[5] += fmaxf(sB_.y + pb[5], 0.f);
        acc[6] += fmaxf(sB_.z + pb[6], 0.f);
        acc[7] += fmaxf(sB_.w + pb[7], 0.f);
    }
    unsigned int w0 = (unsigned int)f2bf(acc[0] * 0.125f) | ((unsigned int)f2bf(acc[1] * 0.125f) << 16);
    unsigned int w1 = (unsigned int)f2bf(acc[2] * 0.125f) | ((unsigned int)f2bf(acc[3] * 0.125f) << 16);
    unsigned int w2 = (unsigned int)f2bf(acc[4] * 0.125f) | ((unsigned int)f2bf(acc[5] * 0.125f) << 16);
    unsigned int w3 = (unsigned int)f2bf(acc[6] * 0.125f) | ((unsigned int)f2bf(acc[7] * 0.125f) << 16);
    size_t dst = ((size_t)blockIdx.x * 48 + (hc >> 3)) * 4096
               + (size_t)((hc & 7) * 64 + lane) * 8;
    *(uint4*)(Hb + dst) = make_uint4(w0, w1, w2, w3);
}

// ---- tiled bf16 MFMA GEMM, 3-stage pipeline ----
// A tiled [by][KT][4096]; Bt tiled [bx][KT][4096]; C row-major MxNd (+bias).
// BM=BN=BK=64, 4 waves (2x2), wave tile 32x32. KT % 3 == 0.
__launch_bounds__(256)
__global__ void gemm_tiled(const unsigned short* __restrict__ A,
                           const unsigned short* __restrict__ Bt,
                           const float* __restrict__ bias,
                           float* __restrict__ C,
                           int Mstore, int Nd, int KT) {
    __shared__ unsigned short sm[3 * 8192];   // 48 KB -> 3 blocks/CU

    const int tid  = threadIdx.x;
    const int lane = tid & 63;
    const int wave = tid >> 6;
    const int wm = wave >> 1, wn = wave & 1;
    const int q = lane >> 4, l16 = lane & 15;

    const unsigned short* Ab = A  + (size_t)blockIdx.y * KT * 4096;
    const unsigned short* Bb = Bt + (size_t)blockIdx.x * KT * 4096;

    f32x4 acc[2][2] = {};

    const int offA = (wm * 32 + l16) * 8;            // + (ks*4+q)*512, +128 for ii=1
    const int offB = 4096 + (wn * 32 + l16) * 8;

    auto stage = [&](int i, unsigned short* d) {     // 4 loads/thread (own vmcnt +4)
        const unsigned short* Ag = Ab + (size_t)i * 4096;
        const unsigned short* Bg = Bb + (size_t)i * 4096;
        gld_lds16(Ag + tid * 8,        d + tid * 8);
        gld_lds16(Ag + 2048 + tid * 8, d + 2048 + tid * 8);
        gld_lds16(Bg + tid * 8,        d + 4096 + tid * 8);
        gld_lds16(Bg + 2048 + tid * 8, d + 6144 + tid * 8);
    };
    auto compute = [&](const unsigned short* buf) {
        #pragma unroll
        for (int ks = 0; ks < 2; ++ks) {
            const int ko = (ks * 4 + q) * 512;
            bf16x8 af0 = *(const bf16x8*)(buf + ko + offA);
            bf16x8 af1 = *(const bf16x8*)(buf + ko + offA + 128);
            bf16x8 bf0 = *(const bf16x8*)(buf + ko + offB);
            bf16x8 bf1 = *(const bf16x8*)(buf + ko + offB + 128);
            acc[0][0] = __builtin_amdgcn_mfma_f32_16x16x32_bf16(af0, bf0, acc[0][0], 0, 0, 0);
            acc[0][1] = __builtin_amdgcn_mfma_f32_16x16x32_bf16(af0, bf1, acc[0][1], 0, 0, 0);
            acc[1][0] = __builtin_amdgcn_mfma_f32_16x16x32_bf16(af1, bf0, acc[1][0], 0, 0, 0);
            acc[1][1] = __builtin_amdgcn_mfma_f32_16x16x32_bf16(af1, bf1, acc[1][1], 0, 0, 0);
        }
    };

    unsigned short* b0 = sm;
    unsigned short* b1 = sm + 8192;
    unsigned short* b2 = sm + 16384;

    stage(0, b0);
    stage(1, b1);
    for (int i = 0; i < KT; i += 3) {                // KT divisible by 3
        // tile i (buf0), stage i+2 -> buf2
        stage(i + 2, b2); WAIT_VM(8);
        BAR();
        compute(b0);
        BAR_LDS();
        // tile i+1 (buf1), stage i+3 -> buf0
        if (i + 3 < KT) { stage(i + 3, b0); WAIT_VM(8); } else { WAIT_VM(4); }
        BAR();
        compute(b1);
        BAR_LDS();
        // tile i+2 (buf2), stage i+4 -> buf1
        if (i + 4 < KT) { stage(i + 4, b1); WAIT_VM(8); }
        else if (i + 3 < KT) { WAIT_VM(4); }
        else { WAIT_VM(0); }
        BAR();
        compute(b2);
        if (i + 3 < KT) BAR_LDS();
    }

    // epilogue: C/D col=lane&15, row=(lane>>4)*4+reg
    const int row0 = blockIdx.y * 64 + wm * 32;
    const int col0 = blockIdx.x * 64 + wn * 32;
    #pragma unroll
    for (int ii = 0; ii < 2; ++ii) {
        #pragma unroll
        for (int jj = 0; jj < 2; ++jj) {
            int col = col0 + jj * 16 + l16;
            float bv = bias ? bias[col] : 0.f;
            #pragma unroll
            for (int r = 0; r < 4; ++r) {
                int row = row0 + ii * 16 + q * 4 + r;
                if (row < Mstore) C[(size_t)row * Nd + col] = acc[ii][jj][r] + bv;
            }
        }
    }
}

extern "C" void kernel_launch(void* const* d_in, const int* in_sizes, int n_in,
                              void* d_out, int out_size, void* d_ws, size_t ws_size,
                              hipStream_t stream) {
    const float* slots  = (const float*)d_in[0];   // 16*8*768
    const float* pos    = (const float*)d_in[1];   // 196*768
    // d_in[2] = map_alpha: unused (softmax over K of identical values = 1/K)
    const float* W1     = (const float*)d_in[3];   // 768*3072
    const float* b1     = (const float*)d_in[4];   // 3072
    const float* W2     = (const float*)d_in[5];   // 3072*768
    const float* b2     = (const float*)d_in[6];   // 768
    float* out = (float*)d_out;                    // 3136*768 f32

    size_t off = 0;
    auto alloc = [&](size_t bytes) {
        void* p = (char*)d_ws + off;
        off += (bytes + 255) & ~(size_t)255;
        return p;
    };
    unsigned short* W1t = (unsigned short*)alloc((size_t)3072 * 768 * 2);   // [48][12] atoms
    unsigned short* W2t = (unsigned short*)alloc((size_t)768 * 3072 * 2);   // [12][48] atoms
    unsigned short* A1  = (unsigned short*)alloc((size_t)384 * 768 * 2);    // [6][12] atoms
    float*          C1  = (float*)alloc((size_t)384 * 3072 * 4);            // row-major
    unsigned short* Hb  = (unsigned short*)alloc((size_t)3136 * 3072 * 2);  // [49][48] atoms

    // 1) prep: tiled weight transposes + tiled A1 pack (626688 tasks)
    k_prep<<<2448, 256, 0, stream>>>(W1, W1t, W2, W2t, slots, pos, A1);
    // 2) C1 = A1 @ W1t^T  (324x3072, KT=12) — 288 blocks
    gemm_tiled<<<dim3(48, 6), 256, 0, stream>>>(A1, W1t, nullptr, C1, 324, 3072, 12);
    // 3) hbar -> Hb atoms
    k_hbar<<<dim3(49, 96), 256, 0, stream>>>(C1, b1, Hb);
    // 4) out = Hb @ W2t^T + b2  (3136x768, KT=48) — 588 blocks
    gemm_tiled<<<dim3(12, 49), 256, 0, stream>>>(Hb, W2t, b2, out, 3136, 768, 48);
}

// Round 7
// 129.888 us; speedup vs baseline: 1.2268x; 1.0571x over previous
//
#include <hip/hip_runtime.h>
#include <hip/hip_bf16.h>
#include <stdint.h>

// B=16, K=8, N=196, D=768, H=3072, DOUT=768
// y[b,n,:] = (mean_k relu(slots[b,k]@W1 + pos[n]@W1 + b1)) @ W2 + b2
// (softmax over K of K-identical values is exactly 1/K; map_alpha unused)
//
// Dispatches:
//  k_prep:     W1->W1t atoms + A1=[slots;pos] atoms (bf16)
//  gemm_tiled: C1 = A1 @ W1t^T      (324x3072, KT=12, XCD nt-swizzle)
//  k_hbar_w2t: Hb atoms (50 row-atoms, clamped) + W2->W2t atoms
//  k_gemm2:    out = Hb @ W2t^T + b2 (BM=128,BN=64, 512 thr, 3-stage,
//              XCD rt-partition swizzle)
// Atom = 64x64 bf16 tile, image [kb 0..7][r 0..63] chunks of 8; off=(kb*64+r)*8.

typedef __attribute__((ext_vector_type(8))) short bf16x8;
typedef __attribute__((ext_vector_type(4))) float f32x4;

#define AS1 __attribute__((address_space(1)))
#define AS3 __attribute__((address_space(3)))

#define WAIT_VM(N) asm volatile("s_waitcnt vmcnt(" #N ")" ::: "memory")
#define BAR()      asm volatile("s_barrier" ::: "memory")
#define BAR_LDS()  asm volatile("s_waitcnt lgkmcnt(0)\ns_barrier" ::: "memory")

static __device__ __forceinline__ void gld_lds16(const void* g, void* l) {
    __builtin_amdgcn_global_load_lds((const AS1 unsigned int*)g,
                                     (AS3 unsigned int*)l, 16, 0, 0);
}

static __device__ __forceinline__ unsigned short f2bf(float f) {
    union { float f; unsigned int u; } v; v.f = f;
    unsigned int u = v.u;
    return (unsigned short)((u + 0x7fffu + ((u >> 16) & 1u)) >> 16);  // RNE
}

// ---------------- prep: W1t tiled transpose + A1 tiled pack ----------------
__global__ void k_prep(const float* __restrict__ W1, unsigned short* __restrict__ W1t,
                       const float* __restrict__ S, const float* __restrict__ P,
                       unsigned short* __restrict__ A1) {
    int idx = blockIdx.x * blockDim.x + threadIdx.x;
    const int C1n = 96 * 3072;          // W1t tasks
    const int PKn = 96 * 384;           // A1 tasks
    if (idx < C1n) {
        int r  = idx % 3072;            // consecutive tid -> consecutive r (coalesced)
        int kc = idx / 3072;            // 8-elem k-chunk (0..95)
        unsigned int po[4];
        #pragma unroll
        for (int j = 0; j < 4; ++j) {
            unsigned short lo = f2bf(W1[(size_t)(kc * 8 + 2 * j) * 3072 + r]);
            unsigned short hi = f2bf(W1[(size_t)(kc * 8 + 2 * j + 1) * 3072 + r]);
            po[j] = (unsigned int)lo | ((unsigned int)hi << 16);
        }
        size_t dst = ((size_t)(r >> 6) * 12 + (kc >> 3)) * 4096
                   + (size_t)((kc & 7) * 64 + (r & 63)) * 8;
        *(uint4*)(W1t + dst) = make_uint4(po[0], po[1], po[2], po[3]);
    } else if (idx < C1n + PKn) {
        int t = idx - C1n;
        int r  = t % 384;
        int kc = t / 384;
        uint4 o = make_uint4(0u, 0u, 0u, 0u);
        if (r < 324) {
            const float* src = (r < 128) ? (S + (size_t)r * 768 + kc * 8)
                                         : (P + (size_t)(r - 128) * 768 + kc * 8);
            float4 a = *(const float4*)(src);
            float4 b = *(const float4*)(src + 4);
            o.x = (unsigned int)f2bf(a.x) | ((unsigned int)f2bf(a.y) << 16);
            o.y = (unsigned int)f2bf(a.z) | ((unsigned int)f2bf(a.w) << 16);
            o.z = (unsigned int)f2bf(b.x) | ((unsigned int)f2bf(b.y) << 16);
            o.w = (unsigned int)f2bf(b.z) | ((unsigned int)f2bf(b.w) << 16);
        }
        size_t dst = ((size_t)(r >> 6) * 12 + (kc >> 3)) * 4096
                   + (size_t)((kc & 7) * 64 + (r & 63)) * 8;
        *(uint4*)(A1 + dst) = o;
    }
}

// ---- hbar (Hb atoms, 50 row-atoms w/ clamp) + W2t conversion, one dispatch ----
__global__ void k_hbar_w2t(const float* __restrict__ C1, const float* __restrict__ b1,
                           unsigned short* __restrict__ Hb,
                           const float* __restrict__ W2, unsigned short* __restrict__ W2t) {
    const int bid = blockIdx.x;
    const int tid = threadIdx.x;
    if (bid >= 4800) {                  // ---- W2t: 1152 blocks ----
        int idx = (bid - 4800) * 256 + tid;     // 0..294911
        int r  = idx % 768;
        int kc = idx / 768;             // 0..383
        unsigned int po[4];
        #pragma unroll
        for (int j = 0; j < 4; ++j) {
            unsigned short lo = f2bf(W2[(size_t)(kc * 8 + 2 * j) * 768 + r]);
            unsigned short hi = f2bf(W2[(size_t)(kc * 8 + 2 * j + 1) * 768 + r]);
            po[j] = (unsigned int)lo | ((unsigned int)hi << 16);
        }
        size_t dst = ((size_t)(r >> 6) * 48 + (kc >> 3)) * 4096
                   + (size_t)((kc & 7) * 64 + (r & 63)) * 8;
        *(uint4*)(W2t + dst) = make_uint4(po[0], po[1], po[2], po[3]);
        return;
    }
    // ---- hbar: 4800 blocks = 50 x 96 ----
    const int bx   = bid % 50;                     // row-atom 0..49
    const int yq   = bid / 50;                     // 0..95
    const int lane = tid & 63;
    const int wv   = tid >> 6;
    const int hc   = yq * 4 + wv;                  // 0..383
    const int h0   = hc * 8;
    int bn = bx * 64 + lane;
    if (bn > 3135) bn = 3135;                      // clamp (dup rows never stored)
    const int b = bn / 196;
    const int n = bn - b * 196;
    const float* prow = C1 + (size_t)(128 + n) * 3072 + h0;
    float4 pA = *(const float4*)(prow);
    float4 pB = *(const float4*)(prow + 4);
    float4 bA = *(const float4*)(b1 + h0);
    float4 bB = *(const float4*)(b1 + h0 + 4);
    float pb[8] = { pA.x + bA.x, pA.y + bA.y, pA.z + bA.z, pA.w + bA.w,
                    pB.x + bB.x, pB.y + bB.y, pB.z + bB.z, pB.w + bB.w };
    float acc[8] = {};
    #pragma unroll
    for (int k = 0; k < 8; ++k) {
        const float* srow = C1 + (size_t)(b * 8 + k) * 3072 + h0;  // wave-broadcast-ish
        float4 sA_ = *(const float4*)(srow);
        float4 sB_ = *(const float4*)(srow + 4);
        acc[0] += fmaxf(sA_.x + pb[0], 0.f);
        acc[1] += fmaxf(sA_.y + pb[1], 0.f);
        acc[2] += fmaxf(sA_.z + pb[2], 0.f);
        acc[3] += fmaxf(sA_.w + pb[3], 0.f);
        acc[4] += fmaxf(sB_.x + pb[4], 0.f);
        acc[5] += fmaxf(sB_.y + pb[5], 0.f);
        acc[6] += fmaxf(sB_.z + pb[6], 0.f);
        acc[7] += fmaxf(sB_.w + pb[7], 0.f);
    }
    unsigned int w0 = (unsigned int)f2bf(acc[0] * 0.125f) | ((unsigned int)f2bf(acc[1] * 0.125f) << 16);
    unsigned int w1 = (unsigned int)f2bf(acc[2] * 0.125f) | ((unsigned int)f2bf(acc[3] * 0.125f) << 16);
    unsigned int w2 = (unsigned int)f2bf(acc[4] * 0.125f) | ((unsigned int)f2bf(acc[5] * 0.125f) << 16);
    unsigned int w3 = (unsigned int)f2bf(acc[6] * 0.125f) | ((unsigned int)f2bf(acc[7] * 0.125f) << 16);
    size_t dst = ((size_t)bx * 48 + (hc >> 3)) * 4096
               + (size_t)((hc & 7) * 64 + lane) * 8;
    *(uint4*)(Hb + dst) = make_uint4(w0, w1, w2, w3);
}

// ---- GEMM1: tiled bf16 MFMA, BM=BN=64, 3-stage, XCD nt-swizzle ----
// grid = 288 (8 xcd x 6 ntPerXcd x 6 rt). A [rt][12][4096]; Bt [nt][12][4096].
__launch_bounds__(256)
__global__ void gemm_tiled(const unsigned short* __restrict__ A,
                           const unsigned short* __restrict__ Bt,
                           float* __restrict__ C,
                           int Mstore, int Nd, int KT) {
    __shared__ unsigned short sm[3 * 8192];   // 48 KB

    const int tid  = threadIdx.x;
    const int lane = tid & 63;
    const int wave = tid >> 6;
    const int wm = wave >> 1, wn = wave & 1;
    const int q = lane >> 4, l16 = lane & 15;

    // swizzle: XCD x = id&7 owns nt in [6x, 6x+6) -> W1t slice L2-resident
    const int id = blockIdx.x;
    const int j  = id >> 3;
    const int nt = (id & 7) * 6 + j % 6;
    const int rt = j / 6;

    const unsigned short* Ab = A  + (size_t)rt * KT * 4096;
    const unsigned short* Bb = Bt + (size_t)nt * KT * 4096;

    f32x4 acc[2][2] = {};
    const int offA = (wm * 32 + l16) * 8;
    const int offB = 4096 + (wn * 32 + l16) * 8;

    auto stage = [&](int i, unsigned short* d) {     // 4 loads/thread
        const unsigned short* Ag = Ab + (size_t)i * 4096;
        const unsigned short* Bg = Bb + (size_t)i * 4096;
        gld_lds16(Ag + tid * 8,        d + tid * 8);
        gld_lds16(Ag + 2048 + tid * 8, d + 2048 + tid * 8);
        gld_lds16(Bg + tid * 8,        d + 4096 + tid * 8);
        gld_lds16(Bg + 2048 + tid * 8, d + 6144 + tid * 8);
    };
    auto compute = [&](const unsigned short* buf) {
        #pragma unroll
        for (int ks = 0; ks < 2; ++ks) {
            const int ko = (ks * 4 + q) * 512;
            bf16x8 af0 = *(const bf16x8*)(buf + ko + offA);
            bf16x8 af1 = *(const bf16x8*)(buf + ko + offA + 128);
            bf16x8 bf0 = *(const bf16x8*)(buf + ko + offB);
            bf16x8 bf1 = *(const bf16x8*)(buf + ko + offB + 128);
            acc[0][0] = __builtin_amdgcn_mfma_f32_16x16x32_bf16(af0, bf0, acc[0][0], 0, 0, 0);
            acc[0][1] = __builtin_amdgcn_mfma_f32_16x16x32_bf16(af0, bf1, acc[0][1], 0, 0, 0);
            acc[1][0] = __builtin_amdgcn_mfma_f32_16x16x32_bf16(af1, bf0, acc[1][0], 0, 0, 0);
            acc[1][1] = __builtin_amdgcn_mfma_f32_16x16x32_bf16(af1, bf1, acc[1][1], 0, 0, 0);
        }
    };

    unsigned short* s0 = sm;
    unsigned short* s1 = sm + 8192;
    unsigned short* s2 = sm + 16384;

    stage(0, s0);
    stage(1, s1);
    for (int i = 0; i < KT; i += 3) {
        stage(i + 2, s2); WAIT_VM(8);
        BAR(); compute(s0); BAR_LDS();
        if (i + 3 < KT) { stage(i + 3, s0); WAIT_VM(8); } else { WAIT_VM(4); }
        BAR(); compute(s1); BAR_LDS();
        if (i + 4 < KT) { stage(i + 4, s1); WAIT_VM(8); }
        else if (i + 3 < KT) { WAIT_VM(4); }
        else { WAIT_VM(0); }
        BAR(); compute(s2);
        if (i + 3 < KT) BAR_LDS();
    }

    const int row0 = rt * 64 + wm * 32;
    const int col0 = nt * 64 + wn * 32;
    #pragma unroll
    for (int ii = 0; ii < 2; ++ii) {
        #pragma unroll
        for (int jj = 0; jj < 2; ++jj) {
            int col = col0 + jj * 16 + l16;
            #pragma unroll
            for (int r = 0; r < 4; ++r) {
                int row = row0 + ii * 16 + q * 4 + r;
                if (row < Mstore) C[(size_t)row * Nd + col] = acc[ii][jj][r];
            }
        }
    }
}

// ---- GEMM2: BM=128, BN=64, 512 threads (8 waves 4x2), 3-stage, rt-XCD swizzle ----
// Hb atoms [50][48][4096]; W2t atoms [12][48][4096]; out 3136x768 f32 + b2.
__launch_bounds__(512)
__global__ void k_gemm2(const unsigned short* __restrict__ Hb,
                        const unsigned short* __restrict__ W2t,
                        const float* __restrict__ b2, float* __restrict__ out) {
    __shared__ unsigned short sm[3 * 12288];   // 72 KB -> 2 blocks/CU (16 waves)

    const int tid  = threadIdx.x;
    const int lane = tid & 63;
    const int wave = tid >> 6;                 // 0..7
    const int wm = wave >> 1, wn = wave & 1;   // wm 0..3 (M), wn 0..1 (N)
    const int q = lane >> 4, l16 = lane & 15;

    // rt-partition swizzle: XCD x = id&7 handles rt in {x, x+8, x+16} (+ tail rt 24)
    const int id = blockIdx.x;
    int rt, nt;
    if (id < 288) { rt = (id / 96) * 8 + (id & 7); nt = (id % 96) >> 3; }
    else          { rt = 24; nt = id - 288; }

    const unsigned short* A0b = Hb  + ((size_t)(2 * rt)     * 48) * 4096;
    const unsigned short* A1b = Hb  + ((size_t)(2 * rt + 1) * 48) * 4096;
    const unsigned short* Bb  = W2t + ((size_t)nt * 48) * 4096;

    f32x4 acc[2][2] = {};

    auto stage = [&](int i, unsigned short* d) {     // 3 loads/thread (512 thr)
        gld_lds16(A0b + (size_t)i * 4096 + tid * 8, d + tid * 8);
        gld_lds16(A1b + (size_t)i * 4096 + tid * 8, d + 4096 + tid * 8);
        gld_lds16(Bb  + (size_t)i * 4096 + tid * 8, d + 8192 + tid * 8);
    };

    // A frag row within 128: r128 = wm*32 + ii*16 + l16 -> atom r128>>6, row r128&63
    const int r0 = wm * 32 + l16;          // ii=0
    const int aoff0 = (r0 >> 6) * 4096 + (r0 & 63) * 8;
    const int r1 = wm * 32 + 16 + l16;     // ii=1
    const int aoff1 = (r1 >> 6) * 4096 + (r1 & 63) * 8;
    const int boff  = 8192 + (wn * 32 + l16) * 8;

    auto compute = [&](const unsigned short* buf) {
        #pragma unroll
        for (int ks = 0; ks < 2; ++ks) {
            const int ko = (ks * 4 + q) * 512;       // k-chunk offset within atom
            bf16x8 af0 = *(const bf16x8*)(buf + aoff0 + ko);
            bf16x8 af1 = *(const bf16x8*)(buf + aoff1 + ko);
            bf16x8 bf0 = *(const bf16x8*)(buf + boff + ko);
            bf16x8 bf1 = *(const bf16x8*)(buf + boff + ko + 128);
            acc[0][0] = __builtin_amdgcn_mfma_f32_16x16x32_bf16(af0, bf0, acc[0][0], 0, 0, 0);
            acc[0][1] = __builtin_amdgcn_mfma_f32_16x16x32_bf16(af0, bf1, acc[0][1], 0, 0, 0);
            acc[1][0] = __builtin_amdgcn_mfma_f32_16x16x32_bf16(af1, bf0, acc[1][0], 0, 0, 0);
            acc[1][1] = __builtin_amdgcn_mfma_f32_16x16x32_bf16(af1, bf1, acc[1][1], 0, 0, 0);
        }
    };

    unsigned short* s0 = sm;
    unsigned short* s1 = sm + 12288;
    unsigned short* s2 = sm + 24576;

    stage(0, s0);
    stage(1, s1);
    for (int i = 0; i < 48; i += 3) {
        stage(i + 2, s2); WAIT_VM(6);
        BAR(); compute(s0); BAR_LDS();
        if (i + 3 < 48) { stage(i + 3, s0); WAIT_VM(6); } else { WAIT_VM(3); }
        BAR(); compute(s1); BAR_LDS();
        if (i + 4 < 48) { stage(i + 4, s1); WAIT_VM(6); }
        else if (i + 3 < 48) { WAIT_VM(3); }
        else { WAIT_VM(0); }
        BAR(); compute(s2);
        if (i + 3 < 48) BAR_LDS();
    }

    // epilogue: C/D col=lane&15, row=(lane>>4)*4+reg
    const int row0 = rt * 128 + wm * 32;
    const int col0 = nt * 64 + wn * 32;
    #pragma unroll
    for (int ii = 0; ii < 2; ++ii) {
        #pragma unroll
        for (int jj = 0; jj < 2; ++jj) {
            int col = col0 + jj * 16 + l16;
            float bv = b2[col];
            #pragma unroll
            for (int r = 0; r < 4; ++r) {
                int row = row0 + ii * 16 + q * 4 + r;
                if (row < 3136) out[(size_t)row * 768 + col] = acc[ii][jj][r] + bv;
            }
        }
    }
}

extern "C" void kernel_launch(void* const* d_in, const int* in_sizes, int n_in,
                              void* d_out, int out_size, void* d_ws, size_t ws_size,
                              hipStream_t stream) {
    const float* slots  = (const float*)d_in[0];   // 16*8*768
    const float* pos    = (const float*)d_in[1];   // 196*768
    // d_in[2] = map_alpha: unused (softmax over K of identical values = 1/K)
    const float* W1     = (const float*)d_in[3];   // 768*3072
    const float* b1     = (const float*)d_in[4];   // 3072
    const float* W2     = (const float*)d_in[5];   // 3072*768
    const float* b2     = (const float*)d_in[6];   // 768
    float* out = (float*)d_out;                    // 3136*768 f32

    size_t off = 0;
    auto alloc = [&](size_t bytes) {
        void* p = (char*)d_ws + off;
        off += (bytes + 255) & ~(size_t)255;
        return p;
    };
    unsigned short* W1t = (unsigned short*)alloc((size_t)3072 * 768 * 2);   // [48][12] atoms
    unsigned short* W2t = (unsigned short*)alloc((size_t)768 * 3072 * 2);   // [12][48] atoms
    unsigned short* A1  = (unsigned short*)alloc((size_t)384 * 768 * 2);    // [6][12] atoms
    float*          C1  = (float*)alloc((size_t)384 * 3072 * 4);            // row-major
    unsigned short* Hb  = (unsigned short*)alloc((size_t)50 * 48 * 4096 * 2); // [50][48] atoms

    // 1) prep: W1t + A1 (331776 tasks, 1296 blocks)
    k_prep<<<1296, 256, 0, stream>>>(W1, W1t, slots, pos, A1);
    // 2) C1 = A1 @ W1t^T (288 blocks, swizzled)
    gemm_tiled<<<288, 256, 0, stream>>>(A1, W1t, C1, 324, 3072, 12);
    // 3) hbar -> Hb atoms (4800 blocks) + W2t conversion (1152 blocks)
    k_hbar_w2t<<<5952, 256, 0, stream>>>(C1, b1, Hb, W2, W2t);
    // 4) out = Hb @ W2t^T + b2 (300 blocks x 512 thr, rt-XCD swizzle)
    k_gemm2<<<300, 512, 0, stream>>>(Hb, W2t, b2, out);
}